// Round 18
// baseline (114.837 us; speedup 1.0000x reference)
//
#include <hip/hip_runtime.h>
#include <hip/hip_bf16.h>

typedef __attribute__((ext_vector_type(8))) short  short8;
typedef __attribute__((ext_vector_type(8))) unsigned short ushort8;
typedef __attribute__((ext_vector_type(4))) unsigned short usv4;
typedef __attribute__((ext_vector_type(4))) float  f32x4;

#define D_DIM 1152
#define O_DIM 256
#define N_TOT 100352
#define XT_H 58
#define XT_ROW (58 * 128)

__device__ __forceinline__ unsigned short f2bf(float f) {
  __hip_bfloat16 h = __float2bfloat16(f);
  return __builtin_bit_cast(unsigned short, h);
}

#define GLOAD_LDS16(g, l)                                              \
  __builtin_amdgcn_global_load_lds(                                    \
      (const __attribute__((address_space(1))) void*)(g),              \
      (__attribute__((address_space(3))) void*)(l), 16, 0, 0)

// ---------------------------------------------------------------------------
// Kernel 1: Wt[o][dn] via LDS-tiled fp32 block-GEMM (proven R4)
// ---------------------------------------------------------------------------
__global__ __launch_bounds__(256) void wt_kernel(
    const float* __restrict__ S1s, const float* __restrict__ U1s,
    const float* __restrict__ U2s, const float* __restrict__ S2s,
    unsigned short* __restrict__ Wt) {
  __shared__ float A_lds[32][64];
  __shared__ float B_lds[32][64];

  const int bo = blockIdx.x & 3;
  const int bd = blockIdx.x >> 2;
  const int o0  = bo << 6;
  const int dn0 = bd << 6;
  const int rr  = dn0 >> 7;
  const int c0  = dn0 & 127;

  const int tid = threadIdx.x;
  const int ty = tid >> 4, tx = tid & 15;

  float acc[4][4] = {};

  for (int kc = 0; kc < 15; ++kc) {
#pragma unroll
    for (int e = 0; e < 8; ++e) {
      const int li = e * 256 + tid;
      const int kk = li >> 6;
      const int xx = li & 63;
      const int k  = kc * 32 + kk;
      float av, bv;
      if (k < 48) {
        av = U1s[k * O_DIM + o0 + xx];
        const int d_old = (c0 + xx) * 9 + rr;
        bv = S1s[(size_t)((k >> 3) * D_DIM + d_old) * 8 + (k & 7)];
      } else {
        const int kq = k - 48;
        av = S2s[(size_t)kq * O_DIM + o0 + xx];
        const int d_old = (c0 + xx) * 9 + rr;
        bv = U2s[(size_t)kq * D_DIM + d_old];
      }
      A_lds[kk][xx] = av;
      B_lds[kk][xx] = bv;
    }
    __syncthreads();
#pragma unroll
    for (int kk = 0; kk < 32; ++kk) {
      f32x4 a = *(const f32x4*)&A_lds[kk][ty << 2];
      f32x4 b = *(const f32x4*)&B_lds[kk][tx << 2];
#pragma unroll
      for (int i = 0; i < 4; ++i)
#pragma unroll
        for (int j = 0; j < 4; ++j)
          acc[i][j] += a[i] * b[j];
    }
    __syncthreads();
  }

#pragma unroll
  for (int i = 0; i < 4; ++i) {
    usv4 v;
#pragma unroll
    for (int j = 0; j < 4; ++j) v[j] = f2bf(acc[i][j] * (1.0f / 6.0f));
    *(usv4*)(Wt + (size_t)(o0 + (ty << 2) + i) * D_DIM + dn0 + (tx << 2)) = v;
  }
}

// ---------------------------------------------------------------------------
// Kernel 2: pad+transpose x[B,C,H,W] fp32 -> x_t[b][ih][iw][c] bf16 (proven R4)
// ---------------------------------------------------------------------------
__global__ __launch_bounds__(256) void pad_kernel(const float* __restrict__ x,
                                                  unsigned short* __restrict__ xt) {
  int blk = blockIdx.x;
  int b = blk / XT_H, ih = blk - b * XT_H;
  unsigned short* dst = xt + (size_t)blk * XT_ROW;
  int tid = threadIdx.x;

  if (ih == 0 || ih == XT_H - 1) {
    ushort8 z;
#pragma unroll
    for (int q = 0; q < 8; ++q) z[q] = 0;
    for (int i = tid; i < XT_ROW / 8; i += 256) ((ushort8*)dst)[i] = z;
    return;
  }

  __shared__ unsigned short lds[128 * 58];
  int h = ih - 1;
  const float* xb = x + (size_t)b * 128 * 3136 + (size_t)h * 56;
#pragma unroll 4
  for (int r = 0; r < 28; ++r) {
    int idx = r * 256 + tid;
    int c = idx / 56, w2 = idx - c * 56;
    lds[c * 58 + w2] = f2bf(xb[(size_t)c * 3136 + w2]);
  }
  __syncthreads();
#pragma unroll 4
  for (int r = 0; r < 29; ++r) {
    int idx = r * 256 + tid;
    int iw = idx >> 7, c = idx & 127;
    unsigned short v = 0;
    if (iw >= 1 && iw <= 56) v = lds[c * 58 + (iw - 1)];
    dst[idx] = v;
  }
}

// ---------------------------------------------------------------------------
// Kernel 3: implicit-im2col GEMM — balanced grid + 2 independent blocks/CU.
// Diagnosis across R4-R16: (1) 392-block grids cap at 77% CU balance; (2) at
// 1 resident block, barrier/drain stalls idle the CU's MFMA pipe with no
// other block to fill (m114's cross-block overlap is m97's actual hiding
// mechanism). Fix: BM=128 x BN=128, grid 1568 (87% balance), 4 waves/block
// (wave-tile 64x64, acc[4][4]), DOUBLE-buffered 2x32KB = 64KB LDS -> TWO
// blocks resident per CU with independent barrier groups.
// Per K-tile: issue STAGE(kt+1 -> buf^1) first (8 gloads), then 16 frag
// ds_reads(kt), then 32 MFMA (~800cyc), then vmcnt(0)-with-slack + ONE
// barrier. Buffer-overwrite safety: frags of kt-1 (from buf^1) completed
// before kt-1's MFMAs (hw lgkmcnt) which precede the barrier we crossed.
// Layout: 128B rows, R7/R11-verified zero-conflict swizzle (granule ^= row&7,
// pre-swizzled global source, linear LDS dest).
// ---------------------------------------------------------------------------
__device__ __forceinline__ constexpr int KOF(int kt) {
  // xt element offset of K-tile kt: (kh*58+kw)*128 + (kt&1)*64
  int rr = kt >> 1;
  return ((rr / 3) * 58 + (rr % 3)) * 128 + (kt & 1) * 64;
}

// stage K-tile kt_ into buffer bf_: 4 A-gloads + 4 B-gloads (4KB each)
#define STAGE(kt_, bf_) do {                                                   \
  _Pragma("unroll")                                                            \
  for (int j = 0; j < 4; ++j) {                                                \
    const int chunk = (w << 2) + j;                                            \
    GLOAD_LDS16(pA[j] + (kt_) * 64,                                            \
                smem + (bf_) * 16384 + (chunk << 9) + sdst);                   \
    GLOAD_LDS16(pB[j] + KOF(kt_),                                              \
                smem + (bf_) * 16384 + 8192 + (chunk << 9) + sdst);            \
  }                                                                            \
} while (0)

// fragment read: 128B rows; granule = (ks*4 + (lane>>4)) ^ (row&7)
#define AFRAG(bf_, row_, ks_)                                                  \
  (*(const short8*)((const char*)smem + (bf_) * 32768 + (row_) * 128 +        \
      (((((ks_) << 2) + (lane >> 4)) ^ ((row_) & 7)) << 4)))
#define BFRAG(bf_, row_, ks_)                                                  \
  (*(const short8*)((const char*)smem + (bf_) * 32768 + 16384 + (row_) * 128 +\
      (((((ks_) << 2) + (lane >> 4)) ^ ((row_) & 7)) << 4)))

__global__ __launch_bounds__(256) void gemm_kernel(
    const unsigned short* __restrict__ Wt, const unsigned short* __restrict__ xt,
    const float* __restrict__ bias, float* __restrict__ out) {
  __shared__ __align__(1024) unsigned short smem[32768];  // 2 x 32KB

  // XCD swizzle (1568 % 8 == 0): pair the 2 o-tiles of each n-tile per XCD.
  const int bid   = blockIdx.x;
  const int lid   = (bid & 7) * 196 + (bid >> 3);
  const int ntile = lid >> 1, otile = lid & 1;
  const int n0 = ntile << 7, o0 = otile << 7;

  const int tid  = threadIdx.x;
  const int w    = tid >> 6;
  const int lane = tid & 63;
  const int wr   = (w >> 1) << 6;   // wave o-offset
  const int wc   = (w & 1) << 6;    // wave n-offset
  const int la15 = lane & 15;

  // linear LDS dest within a chunk (8 rows x 128B): row = lane>>3, gran = lane&7
  const int sdst = ((lane & 7) << 3) + ((lane >> 3) << 6);

  // staging sources (R11-verified): chunk = w*4+j covers rows chunk*8..+7;
  // source granule pre-swizzled = (lane&7) ^ (row&7).
  const unsigned short* pA[4];
  const unsigned short* pB[4];
#pragma unroll
  for (int j = 0; j < 4; ++j) {
    const int chunk = (w << 2) + j;
    const int row   = (chunk << 3) + (lane >> 3);
    const int gs    = (lane & 7) ^ (row & 7);
    pA[j] = Wt + (size_t)(o0 + row) * D_DIM + gs * 8;
    const int n_g = n0 + row;
    const int b   = n_g / 3136;
    const int s   = n_g - b * 3136;
    const int oh  = s / 56, ow = s - oh * 56;
    pB[j] = xt + (((size_t)b * XT_H + oh) * XT_H + ow) * 128 + gs * 8;
  }

  f32x4 acc[4][4] = {};

  // ---- prologue: stage K-tile 0 into buf 0 ----
  STAGE(0, 0);
  asm volatile("s_waitcnt vmcnt(0)" ::: "memory");
  __builtin_amdgcn_s_barrier();

#pragma unroll
  for (int kt = 0; kt < 18; ++kt) {
    const int bf = kt & 1;

    // ---- issue next tile's staging FIRST (hides L2 latency under reads+MFMA)
    if (kt + 1 < 18) STAGE(kt + 1, bf ^ 1);

    // ---- fragment reads for kt ----
    short8 af[4][2], bfr[4][2];
#pragma unroll
    for (int m = 0; m < 4; ++m) {
      af[m][0] = AFRAG(bf, wr + m * 16 + la15, 0);
      af[m][1] = AFRAG(bf, wr + m * 16 + la15, 1);
    }
#pragma unroll
    for (int n = 0; n < 4; ++n) {
      bfr[n][0] = BFRAG(bf, wc + n * 16 + la15, 0);
      bfr[n][1] = BFRAG(bf, wc + n * 16 + la15, 1);
    }

    // ---- MFMA x32 (compiler inserts lgkmcnt before first use) ----
    __builtin_amdgcn_s_setprio(1);
#pragma unroll
    for (int ks = 0; ks < 2; ++ks)
#pragma unroll
      for (int m = 0; m < 4; ++m)
#pragma unroll
        for (int n = 0; n < 4; ++n)
          acc[m][n] = __builtin_amdgcn_mfma_f32_16x16x32_bf16(
              af[m][ks], bfr[n][ks], acc[m][n], 0, 0, 0);
    __builtin_amdgcn_s_setprio(0);

    // ---- drain own stage loads (issued ~800cyc ago -> cheap); barrier ----
    if (kt + 1 < 18) {
      asm volatile("s_waitcnt vmcnt(0)" ::: "memory");
      __builtin_amdgcn_s_barrier();
    }
  }

  // ---- epilogue: D row = o ((lane>>4)*4+reg), col = n (lane&15) ----
  const int lr = (lane >> 4) << 2;
#pragma unroll
  for (int n = 0; n < 4; ++n) {
    const int ng = n0 + wc + n * 16 + la15;
    const int b  = ng / 3136;
    const int s  = ng - b * 3136;
    float* op = out + (size_t)b * (O_DIM * 3136) + s;
#pragma unroll
    for (int m = 0; m < 4; ++m) {
      const int og = o0 + wr + m * 16 + lr;
#pragma unroll
      for (int r = 0; r < 4; ++r)
        op[(size_t)(og + r) * 3136] = acc[m][n][r] + 2.0f * bias[og + r];
    }
  }
}

// ---------------------------------------------------------------------------
extern "C" void kernel_launch(void* const* d_in, const int* in_sizes, int n_in,
                              void* d_out, int out_size, void* d_ws, size_t ws_size,
                              hipStream_t stream) {
  const float* x    = (const float*)d_in[0];
  const float* S1s  = (const float*)d_in[1];
  const float* U1s  = (const float*)d_in[2];
  const float* U2s  = (const float*)d_in[3];
  const float* S2s  = (const float*)d_in[4];
  const float* bias = (const float*)d_in[5];
  float* out = (float*)d_out;
  (void)ws_size;

  unsigned short* xt = (unsigned short*)d_ws;
  unsigned short* Wt = (unsigned short*)((char*)d_ws + (size_t)32 * XT_H * XT_ROW * 2);

  pad_kernel<<<dim3(32 * XT_H), dim3(256), 0, stream>>>(x, xt);
  wt_kernel<<<dim3(72), dim3(256), 0, stream>>>(S1s, U1s, U2s, S2s, Wt);
  gemm_kernel<<<dim3(1568), dim3(256), 0, stream>>>(Wt, xt, bias, out);
}